// Round 8
// baseline (1218.511 us; speedup 1.0000x reference)
//
#include <hip/hip_runtime.h>
#include <hip/hip_bf16.h>

typedef __hip_bfloat16 bf16;
typedef __attribute__((ext_vector_type(8))) short short8;   // 8 bf16 = 4 VGPRs
typedef __attribute__((ext_vector_type(4))) float float4v;  // MFMA C/D
typedef __attribute__((ext_vector_type(4))) short short4v;

__device__ __forceinline__ short f2bs(float x) {
    bf16 b = __float2bfloat16(x);
    return *reinterpret_cast<short*>(&b);
}
__device__ __forceinline__ float bs2f(short s) {
    bf16 b = *reinterpret_cast<bf16*>(&s);
    return __bfloat162float(b);
}

// ---------------- preprocessing: f32 -> padded bf16 layouts ----------------

__global__ __launch_bounds__(256) void conv_wleaf(
    const float* __restrict__ src, short* __restrict__ dst)
{
    const int idx = blockIdx.x * 256 + threadIdx.x;      // 320*320
    if (idx >= 320 * 320) return;
    const int row = idx / 320, k = idx - row * 320;
    dst[idx] = (row < 300 && k < 300) ? f2bs(src[row * 300 + k]) : (short)0;
}

__global__ __launch_bounds__(256) void conv_wh(
    const float* __restrict__ src, short* __restrict__ dst)
{
    const int idx = blockIdx.x * 256 + threadIdx.x;      // 320*640
    if (idx >= 320 * 640) return;
    const int row = idx / 640, k = idx - row * 640;
    float v = 0.f;
    if (row < 300) {
        if (k < 300)                  v = src[row * 600 + k];
        else if (k >= 320 && k < 620) v = src[row * 600 + k - 20];
    }
    dst[idx] = f2bs(v);
}

__global__ __launch_bounds__(320) void conv_bias(
    const float* __restrict__ src, float* __restrict__ dst)
{
    const int i = threadIdx.x;
    if (i < 320) dst[i] = (i < 300) ? src[i] : 0.f;
}

// ---------------- fused half-tree kernel ----------------
// One block = one (tree, half): 128 leaves -> leaf GEMM -> 7 combine levels,
// all intermediates in LDS. 512 thr = 8 waves: wm = w>>2 (M-split 2),
// wn = w&3 (4 x 80-col groups). Wave tile per level: MT 16-row tiles x 5
// N-tiles of v_mfma_f32_16x16x32_bf16, swapped operands (R6/R7-verified):
// acc[t][u] reg r4 = C[row = tile_t + (lane&15)][col = tile_u + kq*4 + r4].
// LDS row stride 328 shorts (656 B): 16-B granule step 41 (odd mod 8) ->
// 16-row-strided ds_read_b128 is 2-way (free); pair-strided (tree levels) 4-way.
// K-loops have NO barriers (A read-only LDS, B global/L2) -> compiler
// pipelines with fine-grained vmcnt. One barrier per level.
#define LSTR 328

template <int MT, int MSPLIT, bool GOUT>
__device__ __forceinline__ void level_gemm(
    const short* I, short* O, const short* __restrict__ Wg,
    const float4v* bias, int wm, int wn, int mq, int kq, short* gout)
{
    if (wm < MSPLIT) {
        float4v acc[MT][5];
#pragma unroll
        for (int t = 0; t < MT; ++t)
#pragma unroll
            for (int u = 0; u < 5; ++u) acc[t][u] = (float4v)0.f;

        const char* bp[5];
#pragma unroll
        for (int u = 0; u < 5; ++u)
            bp[u] = (const char*)Wg + (long)(wn * 80 + u * 16 + mq) * 1280
                    + kq * 16;
#pragma unroll
        for (int kc = 0; kc < 20; ++kc) {
            short8 b[5], a[MT];
#pragma unroll
            for (int u = 0; u < 5; ++u)
                b[u] = *(const short8*)(bp[u] + kc * 64);
#pragma unroll
            for (int t = 0; t < MT; ++t) {
                const int m   = (wm * MT + t) * 16 + mq;
                const int row = 2 * m + (kc >= 10 ? 1 : 0);
                a[t] = *(const short8*)&I[row * LSTR + (kc % 10) * 32 + kq * 8];
            }
#pragma unroll
            for (int u = 0; u < 5; ++u)
#pragma unroll
                for (int t = 0; t < MT; ++t)
                    acc[t][u] = __builtin_amdgcn_mfma_f32_16x16x32_bf16(
                        b[u], a[t], acc[t][u], 0, 0, 0);
        }
#pragma unroll
        for (int t = 0; t < MT; ++t) {
            const int m = (wm * MT + t) * 16 + mq;
#pragma unroll
            for (int u = 0; u < 5; ++u) {
                const int colb = wn * 80 + u * 16 + kq * 4;
                short4v sv;
#pragma unroll
                for (int j = 0; j < 4; ++j)
                    sv[j] = f2bs(acc[t][u][j] + bias[u][j]);
                if (GOUT) {
                    if (m == 0) *(short4v*)&gout[colb] = sv;   // root row only
                } else {
                    *(short4v*)&O[m * LSTR + colb] = sv;
                }
            }
        }
    }
    __syncthreads();
}

__global__ __launch_bounds__(512, 2) void tree_kernel(
    const int* __restrict__ wid, const float* __restrict__ emb,
    const short* __restrict__ Bleaf, const short* __restrict__ Bh,
    const float* __restrict__ biasp, short* __restrict__ groots)
{
    __shared__ __align__(16) short bufA[128 * LSTR];   // 83,968 B
    __shared__ __align__(16) short bufB[64 * LSTR];    // 41,984 B

    const int tid  = threadIdx.x;
    const int lane = tid & 63;
    const int w    = tid >> 6;          // 0..7
    const int wm   = w >> 2;            // M-split
    const int wn   = w & 3;             // N-group (80 cols)
    const int mq   = lane & 15;
    const int kq   = lane >> 4;
    const int half = blockIdx.x & 1;
    const int tree = blockIdx.x >> 1;
    const int leaf0 = tree * 256 + half * 128;

    float4v bias[5];
#pragma unroll
    for (int u = 0; u < 5; ++u)
        bias[u] = *(const float4v*)&biasp[wn * 80 + u * 16 + kq * 4];

    // ---- leaf GEMM in two 64-row halves: E staged f32->bf16 into bufB,
    //      H0 accumulated into bufA (no bias) ----
    for (int hh = 0; hh < 2; ++hh) {
        for (int task = tid; task < 64 * 80; task += 512) {
            const int r  = task / 80;
            const int c4 = task - r * 80;
            short4v v = (short4v)(short)0;
            if (c4 < 75) {
                const float4v f = *(const float4v*)
                    &emb[(long)wid[leaf0 + hh * 64 + r] * 300 + c4 * 4];
#pragma unroll
                for (int j = 0; j < 4; ++j) v[j] = f2bs(f[j]);
            }
            *(short4v*)&bufB[r * LSTR + c4 * 4] = v;
        }
        __syncthreads();

        float4v acc[2][5];
#pragma unroll
        for (int t = 0; t < 2; ++t)
#pragma unroll
            for (int u = 0; u < 5; ++u) acc[t][u] = (float4v)0.f;

        const char* bp[5];
#pragma unroll
        for (int u = 0; u < 5; ++u)
            bp[u] = (const char*)Bleaf + (long)(wn * 80 + u * 16 + mq) * 640
                    + kq * 16;
#pragma unroll
        for (int kc = 0; kc < 10; ++kc) {
            short8 b[5], a[2];
#pragma unroll
            for (int u = 0; u < 5; ++u)
                b[u] = *(const short8*)(bp[u] + kc * 64);
#pragma unroll
            for (int t = 0; t < 2; ++t) {
                const int row = wm * 32 + t * 16 + mq;
                a[t] = *(const short8*)&bufB[row * LSTR + kc * 32 + kq * 8];
            }
#pragma unroll
            for (int u = 0; u < 5; ++u)
#pragma unroll
                for (int t = 0; t < 2; ++t)
                    acc[t][u] = __builtin_amdgcn_mfma_f32_16x16x32_bf16(
                        b[u], a[t], acc[t][u], 0, 0, 0);
        }
#pragma unroll
        for (int t = 0; t < 2; ++t) {
            const int row = hh * 64 + wm * 32 + t * 16 + mq;
#pragma unroll
            for (int u = 0; u < 5; ++u) {
                const int colb = wn * 80 + u * 16 + kq * 4;
                short4v sv;
#pragma unroll
                for (int j = 0; j < 4; ++j) sv[j] = f2bs(acc[t][u][j]);
                *(short4v*)&bufA[row * LSTR + colb] = sv;
            }
        }
        __syncthreads();
    }

    // ---- combine levels: ping-pong bufA <-> bufB; junk rows (finite) in
    //      16-row-padded tail levels never feed valid rows ----
    short* gout = groots + (long)(tree * 2 + half) * 320;
    level_gemm<2, 2, false>(bufA, bufB, Bh, bias, wm, wn, mq, kq, nullptr); // 64
    level_gemm<1, 2, false>(bufB, bufA, Bh, bias, wm, wn, mq, kq, nullptr); // 32
    level_gemm<1, 1, false>(bufA, bufB, Bh, bias, wm, wn, mq, kq, nullptr); // 16
    level_gemm<1, 1, false>(bufB, bufA, Bh, bias, wm, wn, mq, kq, nullptr); // 8v
    level_gemm<1, 1, false>(bufA, bufB, Bh, bias, wm, wn, mq, kq, nullptr); // 4v
    level_gemm<1, 1, false>(bufB, bufA, Bh, bias, wm, wn, mq, kq, nullptr); // 2v
    level_gemm<1, 1, true >(bufA, nullptr, Bh, bias, wm, wn, mq, kq, gout); // 1v
}

// ---------------- cross-half combine (R7-verified mfma_gemm) ----------------
template <int KE, bool GATHER, bool BIAS>
__global__ __launch_bounds__(256, 3) void mfma_gemm(
    const short* __restrict__ Xsrc, const int* __restrict__ wid,
    const short* __restrict__ emb, const short* __restrict__ Wp,
    const float* __restrict__ biasp, short* __restrict__ out)
{
    __shared__ __align__(16) short As[128 * 32];
    __shared__ __align__(16) short Bs[160 * 32];

    const int tid  = threadIdx.x;
    const int lane = tid & 63;
    const int w    = tid >> 6;
    const int wm   = w >> 1, wn = w & 1;
    const long m0  = (long)blockIdx.x * 128;
    const int  nb  = blockIdx.y;

    const int s_q   = lane & 3;
    const int r_off = lane >> 2;

    const char* gsrc[5];
    char*       ldst[5];
    int ng = 0;
#pragma unroll
    for (int j = 0; j < 5; ++j) {
        const int g = w + 4 * j;
        if (g >= 18) break;
        if (g < 8) {
            const int r = g * 16 + r_off;
            const int q = s_q ^ ((r >> 1) & 3);
            long base;
            if (GATHER) base = (long)wid[m0 + r] * 640;
            else        base = (m0 + r) * (long)(KE * 2);
            gsrc[ng] = (const char*)(GATHER ? emb : Xsrc) + base + q * 16;
            ldst[ng] = (char*)As + g * 1024;
        } else {
            const int r = (g - 8) * 16 + r_off;
            const int q = s_q ^ ((r >> 1) & 3);
            const int n = nb * 160 + r;
            gsrc[ng] = (const char*)Wp + (long)n * (KE * 2) + q * 16;
            ldst[ng] = (char*)Bs + (g - 8) * 1024;
        }
        ++ng;
    }

    const short* fA[4];
#pragma unroll
    for (int t = 0; t < 4; ++t) {
        const int row = wm * 64 + t * 16 + (lane & 15);
        const int s   = (lane >> 4) ^ ((row >> 1) & 3);
        fA[t] = &As[row * 32 + s * 8];
    }
    const short* fB[5];
#pragma unroll
    for (int u = 0; u < 5; ++u) {
        const int n = wn * 80 + u * 16 + (lane & 15);
        const int s = (lane >> 4) ^ ((n >> 1) & 3);
        fB[u] = &Bs[n * 32 + s * 8];
    }

    float4v acc[4][5];
#pragma unroll
    for (int t = 0; t < 4; ++t)
#pragma unroll
        for (int u = 0; u < 5; ++u) acc[t][u] = (float4v)0.f;

    for (int kc = 0; kc < KE / 32; ++kc) {
        if (kc) __syncthreads();
        const int off = kc * 64;
#pragma unroll
        for (int j = 0; j < 5; ++j)
            if (j < ng) __builtin_amdgcn_global_load_lds(
                (const __attribute__((address_space(1))) void*)(gsrc[j] + off),
                (__attribute__((address_space(3))) void*)ldst[j], 16, 0, 0);
        __syncthreads();

        short8 a[4], b[5];
#pragma unroll
        for (int t = 0; t < 4; ++t) a[t] = *(const short8*)fA[t];
#pragma unroll
        for (int u = 0; u < 5; ++u) b[u] = *(const short8*)fB[u];
#pragma unroll
        for (int u = 0; u < 5; ++u)
#pragma unroll
            for (int t = 0; t < 4; ++t)
                acc[t][u] = __builtin_amdgcn_mfma_f32_16x16x32_bf16(
                    b[u], a[t], acc[t][u], 0, 0, 0);
    }

    const int mq = lane & 15, kq = lane >> 4;
#pragma unroll
    for (int t = 0; t < 4; ++t) {
        const long row = m0 + wm * 64 + t * 16 + mq;
#pragma unroll
        for (int u = 0; u < 5; ++u) {
            const int colb = nb * 160 + wn * 80 + u * 16 + kq * 4;
            float4v bv = (float4v)0.f;
            if (BIAS) bv = *(const float4v*)&biasp[colb];
            short4v s;
#pragma unroll
            for (int r4 = 0; r4 < 4; ++r4)
                s[r4] = f2bs(acc[t][u][r4] + bv[r4]);
            *(short4v*)&out[row * 320 + colb] = s;
        }
    }
}

// ---------------- classifier ----------------
__global__ __launch_bounds__(64) void cls_kernel(
    const short* __restrict__ roots, const float* __restrict__ W_cls,
    const float* __restrict__ b_cls, float* __restrict__ out)
{
    const int b    = blockIdx.x;
    const int lane = threadIdx.x;
    const short* row = roots + (long)b * 640;

    float a0 = 0.f, a1 = 0.f, a2 = 0.f;
#pragma unroll
    for (int i = 0; i < 10; ++i) {
        const int k = lane + 64 * i;
        if (k < 600) {
            const int col = (k < 300) ? k : k + 20;
            const float f = 1.f / (1.f + __expf(-bs2f(row[col])));
            a0 += f * W_cls[k];
            a1 += f * W_cls[600 + k];
            a2 += f * W_cls[1200 + k];
        }
    }
#pragma unroll
    for (int off = 32; off > 0; off >>= 1) {
        a0 += __shfl_down(a0, off);
        a1 += __shfl_down(a1, off);
        a2 += __shfl_down(a2, off);
    }
    if (lane == 0) {
        const float l0 = a0 + b_cls[0];
        const float l1 = a1 + b_cls[1];
        const float l2 = a2 + b_cls[2];
        const float m  = fmaxf(l0, fmaxf(l1, l2));
        const float s  = __expf(l0 - m) + __expf(l1 - m) + __expf(l2 - m);
        const float ls = m + __logf(s);
        out[b * 3 + 0] = l0 - ls;
        out[b * 3 + 1] = l1 - ls;
        out[b * 3 + 2] = l2 - ls;
    }
}

extern "C" void kernel_launch(void* const* d_in, const int* in_sizes, int n_in,
                              void* d_out, int out_size, void* d_ws, size_t ws_size,
                              hipStream_t stream)
{
    const int*   wid    = (const int*)d_in[0];     // (512,2,256) int32
    const float* emb    = (const float*)d_in[1];   // (50000,300) f32
    const float* W_leaf = (const float*)d_in[2];   // (300,300)
    const float* W_h    = (const float*)d_in[3];   // (300,600)
    const float* b_h    = (const float*)d_in[4];   // (300,)
    const float* W_cls  = (const float*)d_in[5];   // (3,600)
    const float* b_cls  = (const float*)d_in[6];   // (3,)
    float* outp = (float*)d_out;                   // (512,3) f32

    (void)in_sizes; (void)n_in; (void)out_size; (void)ws_size;

    // ws layout (total < 3 MB):
    //   groots @ 0         : 2048*320*2 = 1,310,720  (half-tree roots; pairs
    //            per tree -> rows 2t,2t+1 = contiguous 640 for combine)
    //   troots @ 1,310,720 : 1024*320*2 =   655,360
    //   Bleaf  @ 1,966,080 : 320*320*2  =   204,800
    //   Bh     @ 2,170,880 : 320*640*2  =   409,600
    //   biasp  @ 2,580,480 : 320*4      =     1,280
    char* ws = (char*)d_ws;
    short* groots = (short*)(ws);
    short* troots = (short*)(ws + 1310720);
    short* Bleaf  = (short*)(ws + 1966080);
    short* Bh     = (short*)(ws + 2170880);
    float* biasp  = (float*)(ws + 2580480);

    conv_wleaf<<<(320 * 320) / 256, 256, 0, stream>>>(W_leaf, Bleaf);
    conv_wh   <<<(320 * 640) / 256, 256, 0, stream>>>(W_h, Bh);
    conv_bias <<<1, 320, 0, stream>>>(b_h, biasp);

    // fused: 2048 half-trees, everything through level 7 in LDS
    tree_kernel<<<2048, 512, 0, stream>>>(wid, emb, Bleaf, Bh, biasp, groots);

    // cross-half combine: troots(1024,320) = groots-pairs(1024,640) @ Bh^T + b
    mfma_gemm<640, false, true><<<dim3(8, 2), 256, 0, stream>>>(
        groots, nullptr, nullptr, Bh, biasp, troots);

    cls_kernel<<<512, 64, 0, stream>>>(troots, W_cls, b_cls, outp);
}

// Round 9
// 494.733 us; speedup vs baseline: 2.4630x; 2.4630x over previous
//
#include <hip/hip_runtime.h>
#include <hip/hip_bf16.h>

typedef __hip_bfloat16 bf16;
typedef __attribute__((ext_vector_type(8))) short short8;   // 8 bf16 = 4 VGPRs
typedef __attribute__((ext_vector_type(4))) float float4v;  // MFMA C/D
typedef __attribute__((ext_vector_type(4))) short short4v;

__device__ __forceinline__ short f2bs(float x) {
    bf16 b = __float2bfloat16(x);
    return *reinterpret_cast<short*>(&b);
}
__device__ __forceinline__ float bs2f(short s) {
    bf16 b = *reinterpret_cast<bf16*>(&s);
    return __bfloat162float(b);
}

#define GLL16(g, l) __builtin_amdgcn_global_load_lds(                      \
    (const __attribute__((address_space(1))) void*)(g),                    \
    (__attribute__((address_space(3))) void*)(l), 16, 0, 0)

// ---------------- preprocessing: f32 -> padded bf16 layouts ----------------

__global__ __launch_bounds__(256) void conv_emb(
    const float* __restrict__ src, short* __restrict__ dst)
{
    const int idx = blockIdx.x * 256 + threadIdx.x;      // 50000*80
    if (idx >= 50000 * 80) return;
    const int row = idx / 80;
    const int k4  = (idx - row * 80) * 4;
    short4v v;
#pragma unroll
    for (int j = 0; j < 4; ++j)
        v[j] = (k4 + j < 300) ? f2bs(src[(long)row * 300 + k4 + j]) : (short)0;
    *(short4v*)&dst[(long)row * 320 + k4] = v;
}

__global__ __launch_bounds__(256) void conv_wleaf(
    const float* __restrict__ src, short* __restrict__ dst)
{
    const int idx = blockIdx.x * 256 + threadIdx.x;      // 320*320
    if (idx >= 320 * 320) return;
    const int row = idx / 320, k = idx - row * 320;
    dst[idx] = (row < 300 && k < 300) ? f2bs(src[row * 300 + k]) : (short)0;
}

__global__ __launch_bounds__(256) void conv_wh(
    const float* __restrict__ src, short* __restrict__ dst)
{
    const int idx = blockIdx.x * 256 + threadIdx.x;      // 320*640
    if (idx >= 320 * 640) return;
    const int row = idx / 640, k = idx - row * 640;
    float v = 0.f;
    if (row < 300) {
        if (k < 300)                  v = src[row * 600 + k];
        else if (k >= 320 && k < 620) v = src[row * 600 + k - 20];
    }
    dst[idx] = f2bs(v);
}

__global__ __launch_bounds__(320) void conv_bias(
    const float* __restrict__ src, float* __restrict__ dst)
{
    const int i = threadIdx.x;
    if (i < 320) dst[i] = (i < 300) ? src[i] : 0.f;
}

// ---------------- MFMA GEMM (R5 structure + R6 packed epilogue) ------------
// out(M,320 bf16) = X(M,KE bf16) @ Wp(320,KE bf16)^T (+ biasp), KE in {320,640}.
// Block: 256 thr = 4 waves 2x2; tile M=128 x N=320 (FULL N -> ideal writes).
// Wave: 64x160 = 4 M-tiles x 10 N-tiles of v_mfma_f32_16x16x32_bf16.
// Single-buffer LDS, GLL16 width-16 staging, XOR k-quarter swizzle.
// MFMA operands swapped (b,a) [R6-verified]: acc[t][u] reg r4 =
//   C[row = t-tile + (lane&15)][col = u-tile + (lane>>4)*4 + r4]
// -> packed 8B stores, full-cache-line write coverage (WRITE_SIZE ideal, R6).
template <int KE, bool GATHER, bool BIAS>
__global__ __launch_bounds__(256, 2) void mfma_gemm(
    const short* __restrict__ Xsrc, const int* __restrict__ wid,
    const short* __restrict__ emb, const short* __restrict__ Wp,
    const float* __restrict__ biasp, short* __restrict__ out)
{
    __shared__ __align__(16) short As[128 * 32];   // [row][slot] 64B rows
    __shared__ __align__(16) short Bs[320 * 32];

    const int tid  = threadIdx.x;
    const int lane = tid & 63;
    const int w    = tid >> 6;
    const int wm   = w >> 1, wn = w & 1;
    const long m0  = (long)blockIdx.x * 128;

    const int s_q   = lane & 3;     // lane's LDS k-quarter slot
    const int r_off = lane >> 2;    // row within 16-row staging group

    // staging global pointers (chunk-invariant base)
    const char* gA[2];
#pragma unroll
    for (int j = 0; j < 2; ++j) {
        const int r = (w * 2 + j) * 16 + r_off;            // A row 0..127
        const int q = s_q ^ ((r >> 1) & 3);                // global k-quarter
        if (GATHER) {
            const long widx = wid[m0 + r];
            gA[j] = (const char*)emb + widx * 640 + q * 16;
        } else {
            gA[j] = (const char*)Xsrc + (m0 + r) * (long)(KE * 2) + q * 16;
        }
    }
    const char* gB[5];
#pragma unroll
    for (int j = 0; j < 5; ++j) {
        const int r = (w * 5 + j) * 16 + r_off;            // B row 0..319
        const int q = s_q ^ ((r >> 1) & 3);
        gB[j] = (const char*)Wp + r * (long)(KE * 2) + q * 16;
    }
    char* lA[2]; char* lB[5];
#pragma unroll
    for (int j = 0; j < 2; ++j) lA[j] = (char*)As + (w * 2 + j) * 1024;
#pragma unroll
    for (int j = 0; j < 5; ++j) lB[j] = (char*)Bs + (w * 5 + j) * 1024;

    // fragment LDS addresses (chunk-invariant)
    const short* fA[4];
#pragma unroll
    for (int t = 0; t < 4; ++t) {
        const int row = wm * 64 + t * 16 + (lane & 15);
        const int s   = (lane >> 4) ^ ((row >> 1) & 3);
        fA[t] = &As[row * 32 + s * 8];
    }
    const short* fB[10];
#pragma unroll
    for (int u = 0; u < 10; ++u) {
        const int n = wn * 160 + u * 16 + (lane & 15);
        const int s = (lane >> 4) ^ ((n >> 1) & 3);
        fB[u] = &Bs[n * 32 + s * 8];
    }

    float4v acc[4][10];
#pragma unroll
    for (int t = 0; t < 4; ++t)
#pragma unroll
        for (int u = 0; u < 10; ++u) acc[t][u] = (float4v)0.f;

    for (int kc = 0; kc < KE / 32; ++kc) {
        if (kc) __syncthreads();           // all waves done reading prev chunk
        const int off = kc * 64;
        GLL16(gA[0] + off, lA[0]);
        GLL16(gA[1] + off, lA[1]);
        GLL16(gB[0] + off, lB[0]);
        GLL16(gB[1] + off, lB[1]);
        GLL16(gB[2] + off, lB[2]);
        GLL16(gB[3] + off, lB[3]);
        GLL16(gB[4] + off, lB[4]);
        __syncthreads();                   // drains vmcnt -> LDS visible

        short8 a[4], b[10];
#pragma unroll
        for (int t = 0; t < 4; ++t) a[t] = *(const short8*)fA[t];
#pragma unroll
        for (int u = 0; u < 10; ++u) b[u] = *(const short8*)fB[u];
#pragma unroll
        for (int u = 0; u < 10; ++u)
#pragma unroll
            for (int t = 0; t < 4; ++t)
                acc[t][u] = __builtin_amdgcn_mfma_f32_16x16x32_bf16(
                    b[u], a[t], acc[t][u], 0, 0, 0);   // swapped operands
    }

    // epilogue: row = X row (lane&15); 4 consecutive cols at (lane>>4)*4
    const int mq = lane & 15, kq = lane >> 4;
#pragma unroll
    for (int t = 0; t < 4; ++t) {
        const long row = m0 + wm * 64 + t * 16 + mq;
#pragma unroll
        for (int u = 0; u < 10; ++u) {
            const int colb = wn * 160 + u * 16 + kq * 4;
            float4v bv = (float4v)0.f;
            if (BIAS) bv = *(const float4v*)&biasp[colb];
            short4v s;
#pragma unroll
            for (int r4 = 0; r4 < 4; ++r4)
                s[r4] = f2bs(acc[t][u][r4] + bv[r4]);
            *(short4v*)&out[row * 320 + colb] = s;
        }
    }
}

// ---------------- classifier ----------------
__global__ __launch_bounds__(64) void cls_kernel(
    const short* __restrict__ roots, const float* __restrict__ W_cls,
    const float* __restrict__ b_cls, float* __restrict__ out)
{
    const int b    = blockIdx.x;
    const int lane = threadIdx.x;
    const short* row = roots + (long)b * 640;

    float a0 = 0.f, a1 = 0.f, a2 = 0.f;
#pragma unroll
    for (int i = 0; i < 10; ++i) {
        const int k = lane + 64 * i;
        if (k < 600) {
            const int col = (k < 300) ? k : k + 20;
            const float f = 1.f / (1.f + __expf(-bs2f(row[col])));
            a0 += f * W_cls[k];
            a1 += f * W_cls[600 + k];
            a2 += f * W_cls[1200 + k];
        }
    }
#pragma unroll
    for (int off = 32; off > 0; off >>= 1) {
        a0 += __shfl_down(a0, off);
        a1 += __shfl_down(a1, off);
        a2 += __shfl_down(a2, off);
    }
    if (lane == 0) {
        const float l0 = a0 + b_cls[0];
        const float l1 = a1 + b_cls[1];
        const float l2 = a2 + b_cls[2];
        const float m  = fmaxf(l0, fmaxf(l1, l2));
        const float s  = __expf(l0 - m) + __expf(l1 - m) + __expf(l2 - m);
        const float ls = m + __logf(s);
        out[b * 3 + 0] = l0 - ls;
        out[b * 3 + 1] = l1 - ls;
        out[b * 3 + 2] = l2 - ls;
    }
}

extern "C" void kernel_launch(void* const* d_in, const int* in_sizes, int n_in,
                              void* d_out, int out_size, void* d_ws, size_t ws_size,
                              hipStream_t stream)
{
    const int*   wid    = (const int*)d_in[0];     // (512,2,256) int32
    const float* emb    = (const float*)d_in[1];   // (50000,300) f32
    const float* W_leaf = (const float*)d_in[2];   // (300,300)
    const float* W_h    = (const float*)d_in[3];   // (300,600)
    const float* b_h    = (const float*)d_in[4];   // (300,)
    const float* W_cls  = (const float*)d_in[5];   // (3,600)
    const float* b_cls  = (const float*)d_in[6];   // (3,)
    float* outp = (float*)d_out;                   // (512,3) f32

    (void)in_sizes; (void)n_in; (void)out_size; (void)ws_size;

    // ws layout (peak 252,273,920 B < 256 MiB; 284 MB layout faulted in R4):
    //   hA     @ 0           : 262144*320*2 = 167,772,160
    //   hB     @ 167,772,160 : 131072*320*2 =  83,886,080
    //   emb_bf @ 167,772,160 : 50000*320*2  =  32,000,000  (aliases hB: dead
    //            after leaf GEMM; hB first written by L1, which runs later)
    //   Bleaf  @ 251,658,240 ; Bh @ 251,863,040 ; biasp @ 252,272,640
    char* ws = (char*)d_ws;
    short* hA     = (short*)(ws);
    short* hB     = (short*)(ws + 167772160);
    short* emb_bf = (short*)(ws + 167772160);
    short* Bleaf  = (short*)(ws + 251658240);
    short* Bh     = (short*)(ws + 251863040);
    float* biasp  = (float*)(ws + 252272640);

    conv_emb  <<<(50000 * 80 + 255) / 256, 256, 0, stream>>>(emb, emb_bf);
    conv_wleaf<<<(320 * 320) / 256, 256, 0, stream>>>(W_leaf, Bleaf);
    conv_wh   <<<(320 * 640) / 256, 256, 0, stream>>>(W_h, Bh);
    conv_bias <<<1, 320, 0, stream>>>(b_h, biasp);

    // Leaf: M = 262144, K' = 320 (gather rows of emb_bf)
    mfma_gemm<320, true, false><<<262144 / 128, 256, 0, stream>>>(
        nullptr, wid, emb_bf, Bleaf, biasp, hA);

    // Tree: node m reads prev rows 2m,2m+1 = contiguous 640 bf16 (pads align
    // with Bh's zero k-columns). K' = 640.
    short* cur = hA;
    short* nxt = hB;
    int nodes = 131072;
    for (int l = 0; l < 8; ++l) {
        mfma_gemm<640, false, true><<<nodes / 128, 256, 0, stream>>>(
            cur, nullptr, nullptr, Bh, biasp, nxt);
        short* t = cur; cur = nxt; nxt = t;
        nodes >>= 1;
    }
    // roots: cur == hA, 1024 rows x 320 -> 512 x 640 view

    cls_kernel<<<512, 64, 0, stream>>>(cur, W_cls, b_cls, outp);
}